// Round 4
// baseline (160.629 us; speedup 1.0000x reference)
//
#include <hip/hip_runtime.h>
#include <math.h>

#define B_ 8
#define S_ 2048
#define D_ 1024
#define H_ 64
#define BS_ (B_ * S_)          // 16384 rows

typedef __attribute__((ext_vector_type(8))) short bf16x8;   // 8 bf16 = 4 VGPRs
typedef __attribute__((ext_vector_type(4))) short bf16x4;   // 4 bf16 = 2 VGPRs
typedef __attribute__((ext_vector_type(4))) float f32x4;

static __device__ __forceinline__ short f2bf(float f) {
    unsigned u = __builtin_bit_cast(unsigned, f);
    u = (u + 0x7fffu + ((u >> 16) & 1u)) >> 16;   // RTNE
    return (short)u;
}

// ---------------------------------------------------------------------------
// Kernel 0: W prep, coalesced transpose via LDS.
// Wt[3][64][1024] bf16 = W^T;  Wq pre-scaled by 0.125*log2(e) so attention
// scores are in log2 domain (softmax uses native exp2).
// ---------------------------------------------------------------------------
__global__ __launch_bounds__(256) void wprep(
    const float* __restrict__ Wq, const float* __restrict__ Wk,
    const float* __restrict__ Wv, short* __restrict__ Wt)
{
    const int o  = blockIdx.x >> 4;        // 0..2
    const int k0 = (blockIdx.x & 15) * 64;
    const float* __restrict__ W = (o == 0) ? Wq : ((o == 1) ? Wk : Wv);
    const float scale = (o == 0) ? 0.125f * 1.44269504088896340736f : 1.0f;

    __shared__ float ls[64][65];
    const int r = threadIdx.x >> 6;        // 0..3
    const int c = threadIdx.x & 63;

    #pragma unroll
    for (int i = 0; i < 16; ++i)
        ls[i * 4 + r][c] = W[(size_t)(k0 + i * 4 + r) * H_ + c];
    __syncthreads();
    #pragma unroll
    for (int i = 0; i < 16; ++i) {
        const int n = i * 4 + r;
        Wt[(size_t)(o * 64 + n) * D_ + k0 + c] = f2bf(ls[c][n] * scale);
    }
}

// ---------------------------------------------------------------------------
// Kernel 1: QKV projection via bf16 MFMA, software-pipelined staging.
// Block: 256 thr / 4 waves. Tile M=16 x N=192 (Q|K|V), BK=64. Grid 1024
// (4 blocks/CU resident -> latency hiding; x read exactly once).
// ---------------------------------------------------------------------------
__global__ __launch_bounds__(256) void qkv_proj(
    const float* __restrict__ x, const short* __restrict__ Wt,
    short* __restrict__ Qb, short* __restrict__ Kb, short* __restrict__ Vt)
{
    __shared__ short xs[16][72];
    __shared__ short wsh[192][72];

    const int t = threadIdx.x;
    const int w = t >> 6, lane = t & 63, col = lane & 15, quad = lane >> 4;
    const int row0 = blockIdx.x * 16;
    const int arow = t >> 4;         // 0..15
    const int akk  = (t & 15) * 4;   // 4-elem chunk along k

    f32x4 acc[3] = {};

    float4 xf;
    bf16x8 wf[6];
    auto load_tile = [&](int k0) {
        xf = *(const float4*)&x[(size_t)(row0 + arow) * D_ + k0 + akk];
        #pragma unroll
        for (int i = 0; i < 6; ++i) {
            const int idx = t + i * 256;
            wf[i] = *(const bf16x8*)&Wt[(size_t)(idx >> 3) * D_ + k0 + (idx & 7) * 8];
        }
    };

    load_tile(0);
    for (int k0 = 0; k0 < D_; k0 += 64) {
        bf16x4 av;
        av[0] = f2bf(xf.x); av[1] = f2bf(xf.y); av[2] = f2bf(xf.z); av[3] = f2bf(xf.w);
        *(bf16x4*)&xs[arow][akk] = av;
        #pragma unroll
        for (int i = 0; i < 6; ++i) {
            const int idx = t + i * 256;
            *(bf16x8*)&wsh[idx >> 3][(idx & 7) * 8] = wf[i];
        }
        __syncthreads();
        if (k0 + 64 < D_) load_tile(k0 + 64);   // in flight during MFMA

        #pragma unroll
        for (int ks = 0; ks < 2; ++ks) {
            const int ka = ks * 32 + quad * 8;
            bf16x8 a0 = *(const bf16x8*)&xs[col][ka];
            #pragma unroll
            for (int nt = 0; nt < 3; ++nt) {
                bf16x8 bfr = *(const bf16x8*)&wsh[w * 48 + nt * 16 + col][ka];
                acc[nt] = __builtin_amdgcn_mfma_f32_16x16x32_bf16(a0, bfr, acc[nt], 0, 0, 0);
            }
        }
        __syncthreads();
    }

    // epilogue: C layout col=lane&15, row=quad*4+reg
    #pragma unroll
    for (int nt = 0; nt < 3; ++nt) {
        const int c = w * 48 + nt * 16 + col;
        const int o = c >> 6, cc = c & 63;
        #pragma unroll
        for (int r = 0; r < 4; ++r) {
            const int row = row0 + quad * 4 + r;
            const short v = f2bf(acc[nt][r]);
            if (o == 0)      Qb[(size_t)row * H_ + cc] = v;
            else if (o == 1) Kb[(size_t)row * H_ + cc] = v;
            else {
                const int b = row >> 11, s = row & 2047;
                Vt[(size_t)(b * 64 + cc) * S_ + s] = v;
            }
        }
    }
}

// ---------------------------------------------------------------------------
// Kernel 2: causal flash attention, bf16 MFMA, fp32 acc, log2-domain softmax.
// Block = 16 queries, 4 waves = 4-way KEY split (wave w: kt = w, w+4, ...).
// Grid 8*128 = 1024 (4 blocks/CU, 16 waves/CU). No barriers in k-loop.
// K register-double-buffered; V loads issued before softmax. 4-way partial
// merge via LDS at the end (waves 1-3 publish, wave 0 combines + stores).
// ---------------------------------------------------------------------------
__global__ __launch_bounds__(256) void attn(
    const short* __restrict__ Qb, const short* __restrict__ Kb,
    const short* __restrict__ Vt, float* __restrict__ outp)
{
    __shared__ short Ps[4][16][72];      // per-wave P tile (bf16)
    __shared__ float pO[3][16][68];      // waves 1-3 partial O
    __shared__ float pml[2][3][16];      // [m|l][wave-1][row]

    const int bi = blockIdx.x;
    const int j  = 127 - (bi >> 3);      // 16-q tile, heaviest first
    const int b  = bi & 7;
    const int t  = threadIdx.x;
    const int w = t >> 6, lane = t & 63, col = lane & 15, quad = lane >> 4;
    const int qbase = j * 16;
    const int nkt = (j + 4) >> 2;        // ceil(16*(j+1)/64)

    // Q fragments (A layout: m=lane&15, k=quad*8+i)
    const size_t qrow = (size_t)(b * S_ + qbase + col) * H_;
    const bf16x8 aq0 = *(const bf16x8*)&Qb[qrow + quad * 8];
    const bf16x8 aq1 = *(const bf16x8*)&Qb[qrow + 32 + quad * 8];

    f32x4 Oacc[4] = {};
    float m[4] = {-INFINITY, -INFINITY, -INFINITY, -INFINITY};
    float l[4] = {0.f, 0.f, 0.f, 0.f};

    const short* __restrict__ Kbb = Kb + (size_t)b * S_ * H_;
    const short* __restrict__ Vtb = Vt + (size_t)b * H_ * S_;

    auto load_K = [&](bf16x8 (&dst)[4][2], int kb) {
        #pragma unroll
        for (int nt = 0; nt < 4; ++nt) {
            const size_t krow = (size_t)(kb + nt * 16 + col) * H_;
            dst[nt][0] = *(const bf16x8*)&Kbb[krow + quad * 8];
            dst[nt][1] = *(const bf16x8*)&Kbb[krow + 32 + quad * 8];
        }
    };

    bf16x8 kc[4][2], kn[4][2];
    if (w < nkt) load_K(kc, w * 64);

    for (int kt = w; kt < nkt; kt += 4) {
        const int kbase = kt * 64;
        const bool more = (kt + 4) < nkt;
        if (more) load_K(kn, kbase + 256);     // prefetch next K tile

        // ---- S = Q K^T (16q x 64k) from register fragments
        f32x4 S[4] = {};
        #pragma unroll
        for (int nt = 0; nt < 4; ++nt) {
            S[nt] = __builtin_amdgcn_mfma_f32_16x16x32_bf16(aq0, kc[nt][0], S[nt], 0, 0, 0);
            S[nt] = __builtin_amdgcn_mfma_f32_16x16x32_bf16(aq1, kc[nt][1], S[nt], 0, 0, 0);
        }

        // ---- issue V loads now; softmax below hides their latency
        bf16x8 vv[2][4];
        #pragma unroll
        for (int ks = 0; ks < 2; ++ks)
            #pragma unroll
            for (int nt = 0; nt < 4; ++nt)
                vv[ks][nt] = *(const bf16x8*)
                    &Vtb[(size_t)(nt * 16 + col) * S_ + kbase + ks * 32 + quad * 8];

        // ---- causal mask (only final, diagonal-overlap tile)
        if (kbase + 63 > qbase) {
            #pragma unroll
            for (int nt = 0; nt < 4; ++nt) {
                const int key = kbase + nt * 16 + col;
                #pragma unroll
                for (int r = 0; r < 4; ++r)
                    if (key > qbase + quad * 4 + r) S[nt][r] = -INFINITY;
            }
        }

        // ---- online softmax, log2 domain (scores pre-scaled by log2(e))
        float alpha[4];
        #pragma unroll
        for (int r = 0; r < 4; ++r) {
            float mx = fmaxf(fmaxf(S[0][r], S[1][r]), fmaxf(S[2][r], S[3][r]));
            mx = fmaxf(mx, __shfl_xor(mx, 1));
            mx = fmaxf(mx, __shfl_xor(mx, 2));
            mx = fmaxf(mx, __shfl_xor(mx, 4));
            mx = fmaxf(mx, __shfl_xor(mx, 8));
            const float mn = fmaxf(m[r], mx);
            alpha[r] = __builtin_amdgcn_exp2f(m[r] - mn);   // first tile: 0
            m[r] = mn;
            float rs = 0.f;
            #pragma unroll
            for (int nt = 0; nt < 4; ++nt) {
                const float p = __builtin_amdgcn_exp2f(S[nt][r] - mn);
                S[nt][r] = p;
                rs += p;
            }
            rs += __shfl_xor(rs, 1);
            rs += __shfl_xor(rs, 2);
            rs += __shfl_xor(rs, 4);
            rs += __shfl_xor(rs, 8);
            l[r] = l[r] * alpha[r] + rs;
        }
        #pragma unroll
        for (int nt = 0; nt < 4; ++nt)
            #pragma unroll
            for (int r = 0; r < 4; ++r) Oacc[nt][r] *= alpha[r];

        // ---- P: C layout -> bf16 -> wave-private LDS (transpose to A layout)
        #pragma unroll
        for (int nt = 0; nt < 4; ++nt)
            #pragma unroll
            for (int r = 0; r < 4; ++r)
                Ps[w][quad * 4 + r][nt * 16 + col] = f2bf(S[nt][r]);
        __asm__ volatile("s_waitcnt lgkmcnt(0)" ::: "memory");

        // ---- O += P V
        #pragma unroll
        for (int ks = 0; ks < 2; ++ks) {
            bf16x8 ap = *(const bf16x8*)&Ps[w][col][ks * 32 + quad * 8];
            #pragma unroll
            for (int nt = 0; nt < 4; ++nt)
                Oacc[nt] = __builtin_amdgcn_mfma_f32_16x16x32_bf16(ap, vv[ks][nt], Oacc[nt], 0, 0, 0);
        }

        if (more) {                       // rotate prefetch buffer
            #pragma unroll
            for (int nt = 0; nt < 4; ++nt) {
                kc[nt][0] = kn[nt][0];
                kc[nt][1] = kn[nt][1];
            }
        }
    }

    // ---- 4-way partial merge (waves 1-3 publish; wave 0 combines + stores)
    __syncthreads();
    if (w > 0) {
        #pragma unroll
        for (int nt = 0; nt < 4; ++nt)
            #pragma unroll
            for (int r = 0; r < 4; ++r)
                pO[w - 1][quad * 4 + r][nt * 16 + col] = Oacc[nt][r];
        if (col == 0) {
            #pragma unroll
            for (int r = 0; r < 4; ++r) {
                pml[0][w - 1][quad * 4 + r] = m[r];
                pml[1][w - 1][quad * 4 + r] = l[r];
            }
        }
    }
    __syncthreads();
    if (w == 0) {
        #pragma unroll
        for (int r = 0; r < 4; ++r) {
            const int row = quad * 4 + r;
            float M = m[r];
            #pragma unroll
            for (int i = 0; i < 3; ++i) M = fmaxf(M, pml[0][i][row]);
            const float a0 = __builtin_amdgcn_exp2f(m[r] - M);
            float ai[3];
            float L = a0 * l[r];
            #pragma unroll
            for (int i = 0; i < 3; ++i) {
                ai[i] = __builtin_amdgcn_exp2f(pml[0][i][row] - M);  // -inf -> 0
                L += ai[i] * pml[1][i][row];
            }
            const float inv = 1.0f / L;
            float* dst = outp + (size_t)(b * S_ + qbase + row) * H_;
            #pragma unroll
            for (int nt = 0; nt < 4; ++nt) {
                float v = a0 * Oacc[nt][r];
                #pragma unroll
                for (int i = 0; i < 3; ++i) v += ai[i] * pO[i][row][nt * 16 + col];
                dst[nt * 16 + col] = v * inv;
            }
        }
    }
}

// ---------------------------------------------------------------------------
extern "C" void kernel_launch(void* const* d_in, const int* in_sizes, int n_in,
                              void* d_out, int out_size, void* d_ws, size_t ws_size,
                              hipStream_t stream)
{
    const float* x  = (const float*)d_in[0];
    const float* Wq = (const float*)d_in[1];
    const float* Wk = (const float*)d_in[2];
    const float* Wv = (const float*)d_in[3];
    float* out = (float*)d_out;

    short* Qb = (short*)d_ws;            // [16384][64] bf16   (2 MB)
    short* Kb = Qb + (size_t)BS_ * H_;   // [16384][64] bf16   (2 MB)
    short* Vt = Kb + (size_t)BS_ * H_;   // [8][64][2048] bf16 (2 MB)
    short* Wt = Vt + (size_t)BS_ * H_;   // [3][64][1024] bf16 (384 KB)

    hipLaunchKernelGGL(wprep,    dim3(48), dim3(256), 0, stream, Wq, Wk, Wv, Wt);
    hipLaunchKernelGGL(qkv_proj, dim3(BS_ / 16), dim3(256), 0, stream, x, Wt, Qb, Kb, Vt);
    hipLaunchKernelGGL(attn,     dim3(B_ * (S_ / 16)), dim3(256), 0, stream, Qb, Kb, Vt, out);
}

// Round 5
// 130.783 us; speedup vs baseline: 1.2282x; 1.2282x over previous
//
#include <hip/hip_runtime.h>
#include <math.h>

#define B_ 8
#define S_ 2048
#define D_ 1024
#define H_ 64
#define BS_ (B_ * S_)          // 16384 rows

typedef __attribute__((ext_vector_type(8))) short bf16x8;   // 8 bf16 = 4 VGPRs
typedef __attribute__((ext_vector_type(4))) float f32x4;

static __device__ __forceinline__ short f2bf(float f) {
    unsigned u = __builtin_bit_cast(unsigned, f);
    u = (u + 0x7fffu + ((u >> 16) & 1u)) >> 16;   // RTNE
    return (short)u;
}

// ---------------------------------------------------------------------------
// Packed fragment layouts (16x16x32 bf16 MFMA, lane = (col=lane&15, quad=lane>>4)):
//  Qp[qtile=row/16][f=0,1][lane][8]   : A-frag  Q[q=16*qt+col][d=f*32+quad*8+j]
//  Kp[ktile=row/64][nt=0..3][ks=0,1][lane][8]
//                                     : B-frag  K[key=64*kt+nt*16+col][d=ks*32+quad*8+j]
//  Vp[ktile][ks=0,1][nt=0..3][lane][8]
//                                     : B-frag  V[key=64*kt+ks*32+quad*8+j][d=nt*16+col]
// Each frag = 1 KB, read by one wave as a single coalesced 16B/lane load.
// ---------------------------------------------------------------------------

// ---------------------------------------------------------------------------
// Kernel 0: W prep, coalesced transpose via LDS.
// Wt[3][64][1024] bf16 = W^T;  Wq pre-scaled by 0.125*log2(e) so attention
// scores are in log2 domain (softmax uses native exp2).
// ---------------------------------------------------------------------------
__global__ __launch_bounds__(256) void wprep(
    const float* __restrict__ Wq, const float* __restrict__ Wk,
    const float* __restrict__ Wv, short* __restrict__ Wt)
{
    const int o  = blockIdx.x >> 4;        // 0..2
    const int k0 = (blockIdx.x & 15) * 64;
    const float* __restrict__ W = (o == 0) ? Wq : ((o == 1) ? Wk : Wv);
    const float scale = (o == 0) ? 0.125f * 1.44269504088896340736f : 1.0f;

    __shared__ float ls[64][65];
    const int r = threadIdx.x >> 6;        // 0..3
    const int c = threadIdx.x & 63;

    #pragma unroll
    for (int i = 0; i < 16; ++i)
        ls[i * 4 + r][c] = W[(size_t)(k0 + i * 4 + r) * H_ + c];
    __syncthreads();
    #pragma unroll
    for (int i = 0; i < 16; ++i) {
        const int n = i * 4 + r;
        Wt[(size_t)(o * 64 + n) * D_ + k0 + c] = f2bf(ls[c][n] * scale);
    }
}

// ---------------------------------------------------------------------------
// Kernel 1: QKV projection via bf16 MFMA. M=32 rows, N=192 (Q|K|V), BK=128
// (8 fat K-iters), depth-1 register prefetch. Grid 512 (2 blocks/CU).
// Epilogue: LDS bounce -> packed fragment outputs (see layouts above).
// ---------------------------------------------------------------------------
__global__ __launch_bounds__(256) void qkv_proj(
    const float* __restrict__ x, const short* __restrict__ Wt,
    short* __restrict__ Qp, short* __restrict__ Kp, short* __restrict__ Vp)
{
    __shared__ short xs[32][136];     // pitch 136 shorts: bank advance 4/row
    __shared__ short wsh[192][136];

    const int t = threadIdx.x;
    const int w = t >> 6, lane = t & 63, col = lane & 15, quad = lane >> 4;
    const int row0 = blockIdx.x * 32;
    const int xrow = t >> 3;          // 0..31
    const int xkc  = (t & 7) * 16;    // 16-float chunk along k

    f32x4 acc[2][3] = {};

    float4 xf[4];
    bf16x8 wf[12];
    auto load_tile = [&](int k0) {
        #pragma unroll
        for (int i = 0; i < 4; ++i)
            xf[i] = *(const float4*)&x[(size_t)(row0 + xrow) * D_ + k0 + xkc + i * 4];
        #pragma unroll
        for (int i = 0; i < 12; ++i) {
            const int idx = t + i * 256;
            wf[i] = *(const bf16x8*)&Wt[(size_t)(idx >> 4) * D_ + k0 + (idx & 15) * 8];
        }
    };

    load_tile(0);
    for (int k0 = 0; k0 < D_; k0 += 128) {
        // commit prefetched regs to LDS
        #pragma unroll
        for (int h = 0; h < 2; ++h) {
            const float4 f0 = xf[h * 2], f1 = xf[h * 2 + 1];
            bf16x8 av;
            av[0] = f2bf(f0.x); av[1] = f2bf(f0.y); av[2] = f2bf(f0.z); av[3] = f2bf(f0.w);
            av[4] = f2bf(f1.x); av[5] = f2bf(f1.y); av[6] = f2bf(f1.z); av[7] = f2bf(f1.w);
            *(bf16x8*)&xs[xrow][xkc + h * 8] = av;
        }
        #pragma unroll
        for (int i = 0; i < 12; ++i) {
            const int idx = t + i * 256;
            *(bf16x8*)&wsh[idx >> 4][(idx & 15) * 8] = wf[i];
        }
        __syncthreads();
        if (k0 + 128 < D_) load_tile(k0 + 128);   // in flight during MFMA

        #pragma unroll
        for (int ks = 0; ks < 4; ++ks) {
            const int ka = ks * 32 + quad * 8;
            bf16x8 a0 = *(const bf16x8*)&xs[col][ka];
            bf16x8 a1 = *(const bf16x8*)&xs[16 + col][ka];
            #pragma unroll
            for (int nt = 0; nt < 3; ++nt) {
                bf16x8 bfr = *(const bf16x8*)&wsh[w * 48 + nt * 16 + col][ka];
                acc[0][nt] = __builtin_amdgcn_mfma_f32_16x16x32_bf16(a0, bfr, acc[0][nt], 0, 0, 0);
                acc[1][nt] = __builtin_amdgcn_mfma_f32_16x16x32_bf16(a1, bfr, acc[1][nt], 0, 0, 0);
            }
        }
        __syncthreads();
    }

    // ---- epilogue: C (32 x 192) -> LDS (overlay on wsh) -> packed frags
    short (*Cs)[200] = (short(*)[200])&wsh[0][0];   // pitch 200: bank adv 4
    #pragma unroll
    for (int mt = 0; mt < 2; ++mt)
        #pragma unroll
        for (int nt = 0; nt < 3; ++nt)
            #pragma unroll
            for (int r = 0; r < 4; ++r)
                Cs[mt * 16 + quad * 4 + r][w * 48 + nt * 16 + col] = f2bf(acc[mt][nt][r]);
    __syncthreads();

    const int qtile = row0 >> 4;          // global 16-row tile
    const int ktg   = row0 >> 6;          // global 64-row tile
    const int half  = (row0 >> 5) & 1;    // which 32-row half of the 64-tile

    if (w < 2) {
        // Q: waves 0,1 -> q-tile (qtile+w), frags f=0,1
        #pragma unroll
        for (int f = 0; f < 2; ++f) {
            bf16x8 v = *(const bf16x8*)&Cs[w * 16 + col][f * 32 + quad * 8];
            *(bf16x8*)&Qp[((size_t)(qtile + w) * 2 + f) * 512 + lane * 8] = v;
        }
    } else {
        // K: waves 2,3 -> ks = w-2, nt = half*2 + {0,1}
        const int ks = w - 2;
        #pragma unroll
        for (int ntl = 0; ntl < 2; ++ntl) {
            const int nt = half * 2 + ntl;
            bf16x8 v = *(const bf16x8*)&Cs[ntl * 16 + col][64 + ks * 32 + quad * 8];
            *(bf16x8*)&Kp[((size_t)(ktg * 4 + nt) * 2 + ks) * 512 + lane * 8] = v;
        }
    }
    {
        // V: wave w -> nt = w, ks = half (keys are this block's 32 rows)
        const int nt = w;
        bf16x8 v;
        #pragma unroll
        for (int jj = 0; jj < 8; ++jj)
            v[jj] = Cs[quad * 8 + jj][128 + nt * 16 + col];
        *(bf16x8*)&Vp[((size_t)(ktg * 2 + half) * 4 + nt) * 512 + lane * 8] = v;
    }
}

// ---------------------------------------------------------------------------
// Kernel 2: causal flash attention, bf16 MFMA, fp32 acc, log2-domain softmax.
// Block = 16 queries, 4 waves = 4-way KEY split (wave w: kt = w, w+4, ...).
// Grid 8*128 = 1024. All frag loads are coalesced 1-KB wave loads from the
// packed Qp/Kp/Vp layouts. b = bi&7 pins each batch to one XCD's L2.
// ---------------------------------------------------------------------------
__global__ __launch_bounds__(256) void attn(
    const short* __restrict__ Qp, const short* __restrict__ Kp,
    const short* __restrict__ Vp, float* __restrict__ outp)
{
    __shared__ short Ps[4][16][72];      // per-wave P tile (bf16)
    __shared__ float pO[3][16][68];      // waves 1-3 partial O
    __shared__ float pml[2][3][16];      // [m|l][wave-1][row]

    const int bi = blockIdx.x;
    const int j  = 127 - (bi >> 3);      // 16-q tile, heaviest first
    const int b  = bi & 7;
    const int t  = threadIdx.x;
    const int w = t >> 6, lane = t & 63, col = lane & 15, quad = lane >> 4;
    const int qbase = j * 16;
    const int nkt = (j + 4) >> 2;        // ceil(16*(j+1)/64)
    const int gbase = b * 32;            // global 64-key tile base for batch b

    // Q fragments: coalesced packed loads
    const short* Qpb = Qp + ((size_t)(b * 128 + j) * 2) * 512;
    const bf16x8 aq0 = *(const bf16x8*)&Qpb[lane * 8];
    const bf16x8 aq1 = *(const bf16x8*)&Qpb[512 + lane * 8];

    f32x4 Oacc[4] = {};
    float m[4] = {-INFINITY, -INFINITY, -INFINITY, -INFINITY};
    float l[4] = {0.f, 0.f, 0.f, 0.f};

    auto load_K = [&](bf16x8 (&dst)[4][2], int g) {
        const short* base = Kp + (size_t)g * 4096;
        #pragma unroll
        for (int nt = 0; nt < 4; ++nt) {
            dst[nt][0] = *(const bf16x8*)&base[nt * 1024 + lane * 8];
            dst[nt][1] = *(const bf16x8*)&base[nt * 1024 + 512 + lane * 8];
        }
    };

    bf16x8 kc[4][2], kn[4][2];
    if (w < nkt) load_K(kc, gbase + w);

    for (int kt = w; kt < nkt; kt += 4) {
        const int kbase = kt * 64;
        const bool more = (kt + 4) < nkt;
        if (more) load_K(kn, gbase + kt + 4);  // prefetch next K tile

        // ---- S = Q K^T (16q x 64k)
        f32x4 S[4] = {};
        #pragma unroll
        for (int nt = 0; nt < 4; ++nt) {
            S[nt] = __builtin_amdgcn_mfma_f32_16x16x32_bf16(aq0, kc[nt][0], S[nt], 0, 0, 0);
            S[nt] = __builtin_amdgcn_mfma_f32_16x16x32_bf16(aq1, kc[nt][1], S[nt], 0, 0, 0);
        }

        // ---- issue V loads now; softmax hides their latency
        const short* vb = Vp + (size_t)(gbase + kt) * 4096;
        bf16x8 vv[2][4];
        #pragma unroll
        for (int ks = 0; ks < 2; ++ks)
            #pragma unroll
            for (int nt = 0; nt < 4; ++nt)
                vv[ks][nt] = *(const bf16x8*)&vb[(ks * 4 + nt) * 512 + lane * 8];

        // ---- causal mask (only final, diagonal-overlap tile)
        if (kbase + 63 > qbase) {
            #pragma unroll
            for (int nt = 0; nt < 4; ++nt) {
                const int key = kbase + nt * 16 + col;
                #pragma unroll
                for (int r = 0; r < 4; ++r)
                    if (key > qbase + quad * 4 + r) S[nt][r] = -INFINITY;
            }
        }

        // ---- online softmax, log2 domain (scores pre-scaled by log2(e))
        float alpha[4];
        #pragma unroll
        for (int r = 0; r < 4; ++r) {
            float mx = fmaxf(fmaxf(S[0][r], S[1][r]), fmaxf(S[2][r], S[3][r]));
            mx = fmaxf(mx, __shfl_xor(mx, 1));
            mx = fmaxf(mx, __shfl_xor(mx, 2));
            mx = fmaxf(mx, __shfl_xor(mx, 4));
            mx = fmaxf(mx, __shfl_xor(mx, 8));
            const float mn = fmaxf(m[r], mx);
            alpha[r] = __builtin_amdgcn_exp2f(m[r] - mn);   // first tile: 0
            m[r] = mn;
            float rs = 0.f;
            #pragma unroll
            for (int nt = 0; nt < 4; ++nt) {
                const float p = __builtin_amdgcn_exp2f(S[nt][r] - mn);
                S[nt][r] = p;
                rs += p;
            }
            rs += __shfl_xor(rs, 1);
            rs += __shfl_xor(rs, 2);
            rs += __shfl_xor(rs, 4);
            rs += __shfl_xor(rs, 8);
            l[r] = l[r] * alpha[r] + rs;
        }
        #pragma unroll
        for (int nt = 0; nt < 4; ++nt)
            #pragma unroll
            for (int r = 0; r < 4; ++r) Oacc[nt][r] *= alpha[r];

        // ---- P: C layout -> bf16 -> wave-private LDS (transpose to A layout)
        #pragma unroll
        for (int nt = 0; nt < 4; ++nt)
            #pragma unroll
            for (int r = 0; r < 4; ++r)
                Ps[w][quad * 4 + r][nt * 16 + col] = f2bf(S[nt][r]);
        __asm__ volatile("s_waitcnt lgkmcnt(0)" ::: "memory");

        // ---- O += P V
        #pragma unroll
        for (int ks = 0; ks < 2; ++ks) {
            bf16x8 ap = *(const bf16x8*)&Ps[w][col][ks * 32 + quad * 8];
            #pragma unroll
            for (int nt = 0; nt < 4; ++nt)
                Oacc[nt] = __builtin_amdgcn_mfma_f32_16x16x32_bf16(ap, vv[ks][nt], Oacc[nt], 0, 0, 0);
        }

        if (more) {                       // rotate prefetch buffer
            #pragma unroll
            for (int nt = 0; nt < 4; ++nt) {
                kc[nt][0] = kn[nt][0];
                kc[nt][1] = kn[nt][1];
            }
        }
    }

    // ---- 4-way partial merge (waves 1-3 publish; wave 0 combines + stores)
    __syncthreads();
    if (w > 0) {
        #pragma unroll
        for (int nt = 0; nt < 4; ++nt)
            #pragma unroll
            for (int r = 0; r < 4; ++r)
                pO[w - 1][quad * 4 + r][nt * 16 + col] = Oacc[nt][r];
        if (col == 0) {
            #pragma unroll
            for (int r = 0; r < 4; ++r) {
                pml[0][w - 1][quad * 4 + r] = m[r];
                pml[1][w - 1][quad * 4 + r] = l[r];
            }
        }
    }
    __syncthreads();
    if (w == 0) {
        #pragma unroll
        for (int r = 0; r < 4; ++r) {
            const int row = quad * 4 + r;
            float M = m[r];
            #pragma unroll
            for (int i = 0; i < 3; ++i) M = fmaxf(M, pml[0][i][row]);
            const float a0 = __builtin_amdgcn_exp2f(m[r] - M);
            float ai[3];
            float L = a0 * l[r];
            #pragma unroll
            for (int i = 0; i < 3; ++i) {
                ai[i] = __builtin_amdgcn_exp2f(pml[0][i][row] - M);  // -inf -> 0
                L += ai[i] * pml[1][i][row];
            }
            const float inv = 1.0f / L;
            float* dst = outp + (size_t)(b * S_ + qbase + row) * H_;
            #pragma unroll
            for (int nt = 0; nt < 4; ++nt) {
                float v = a0 * Oacc[nt][r];
                #pragma unroll
                for (int i = 0; i < 3; ++i) v += ai[i] * pO[i][row][nt * 16 + col];
                dst[nt * 16 + col] = v * inv;
            }
        }
    }
}

// ---------------------------------------------------------------------------
extern "C" void kernel_launch(void* const* d_in, const int* in_sizes, int n_in,
                              void* d_out, int out_size, void* d_ws, size_t ws_size,
                              hipStream_t stream)
{
    const float* x  = (const float*)d_in[0];
    const float* Wq = (const float*)d_in[1];
    const float* Wk = (const float*)d_in[2];
    const float* Wv = (const float*)d_in[3];
    float* out = (float*)d_out;

    short* Qp = (short*)d_ws;            // 1024 qtiles * 2 frags * 512  (2 MB)
    short* Kp = Qp + (size_t)BS_ * H_;   // 256 ktiles * 8 frags * 512   (2 MB)
    short* Vp = Kp + (size_t)BS_ * H_;   // 256 ktiles * 8 frags * 512   (2 MB)
    short* Wt = Vp + (size_t)BS_ * H_;   // [3][64][1024] bf16           (384 KB)

    hipLaunchKernelGGL(wprep,    dim3(48), dim3(256), 0, stream, Wq, Wk, Wv, Wt);
    hipLaunchKernelGGL(qkv_proj, dim3(BS_ / 32), dim3(256), 0, stream, x, Wt, Qp, Kp, Vp);
    hipLaunchKernelGGL(attn,     dim3(B_ * (S_ / 16)), dim3(256), 0, stream, Qp, Kp, Vp, out);
}

// Round 6
// 123.608 us; speedup vs baseline: 1.2995x; 1.0580x over previous
//
#include <hip/hip_runtime.h>
#include <math.h>

#define B_ 8
#define S_ 2048
#define D_ 1024
#define H_ 64
#define BS_ (B_ * S_)          // 16384 rows

typedef __attribute__((ext_vector_type(8))) short bf16x8;   // 8 bf16 = 4 VGPRs
typedef __attribute__((ext_vector_type(4))) short bf16x4;
typedef __attribute__((ext_vector_type(4))) float f32x4;

static __device__ __forceinline__ short f2bf(float f) {
    unsigned u = __builtin_bit_cast(unsigned, f);
    u = (u + 0x7fffu + ((u >> 16) & 1u)) >> 16;   // RTNE
    return (short)u;
}

// ---------------------------------------------------------------------------
// Packed fragment layouts (16x16x32 bf16 MFMA; col=lane&15, quad=lane>>4):
//  Wfp[fid=0..11][ks=0..31][lane][8] : B-frag W[k=ks*32+quad*8+j][n] * scale,
//                                      n = (fid&3)*16+col of matrix o=fid>>2
//  Qp[qtile][f=0,1][lane][8]         : A-frag Q[q=16*qt+col][d=f*32+quad*8+j]
//  Kp[ktile][nt=0..3][ks=0,1][lane][8]: B-frag K[key=64kt+nt*16+col][d=ks*32+quad*8+j]
//  Vp[ktile][ks=0,1][nt=0..3][lane][8]: B-frag V[key=64kt+ks*32+quad*8+j][d=nt*16+col]
// Every frag = 1 KB -> one coalesced 16B/lane wave load.
// ---------------------------------------------------------------------------

// ---------------------------------------------------------------------------
// Kernel 0: W prep -> fragment-packed Wfp. Grid 32 (one block per ks), 256 thr.
// Wq pre-scaled by 0.125*log2(e): scores in log2 domain (softmax uses exp2).
// ---------------------------------------------------------------------------
__global__ __launch_bounds__(256) void wprep(
    const float* __restrict__ Wq, const float* __restrict__ Wk,
    const float* __restrict__ Wv, short* __restrict__ Wfp)
{
    const int ks = blockIdx.x;             // k-slab [ks*32, ks*32+32)
    __shared__ float ws[3][32][68];

    const int t = threadIdx.x;
    const int r  = t >> 3;                 // 0..31
    const int c0 = (t & 7) * 8;
    #pragma unroll
    for (int o = 0; o < 3; ++o) {
        const float* __restrict__ W = (o == 0) ? Wq : ((o == 1) ? Wk : Wv);
        *(float4*)&ws[o][r][c0]     = *(const float4*)&W[(size_t)(ks * 32 + r) * H_ + c0];
        *(float4*)&ws[o][r][c0 + 4] = *(const float4*)&W[(size_t)(ks * 32 + r) * H_ + c0 + 4];
    }
    __syncthreads();

    const int w = t >> 6, lane = t & 63, col = lane & 15, quad = lane >> 4;
    #pragma unroll
    for (int i = 0; i < 3; ++i) {
        const int fid = i * 4 + w;         // 0..11
        const int o = fid >> 2, ntl = fid & 3;
        const float scale = (o == 0) ? 0.125f * 1.4426950408889634f : 1.0f;
        bf16x8 v;
        #pragma unroll
        for (int j = 0; j < 8; ++j)
            v[j] = f2bf(ws[o][quad * 8 + j][ntl * 16 + col] * scale);
        *(bf16x8*)&Wfp[((size_t)fid * 32 + ks) * 512 + lane * 8] = v;
    }
}

// ---------------------------------------------------------------------------
// Kernel 1: QKV projection. M=32 rows/block, grid 512. x (fp32) staged ONCE
// into LDS as bf16 (full K=1024); then a BARRIER-FREE ks-loop: A-frags from
// LDS, B-frags as coalesced 1-KB wave loads from packed Wfp (L2-resident),
// depth-2 W prefetch, depth-1 A prefetch. Epilogue packs Qp/Kp/Vp frags.
// ---------------------------------------------------------------------------
__global__ __launch_bounds__(256) void qkv_proj(
    const float* __restrict__ x, const short* __restrict__ Wfp,
    short* __restrict__ Qp, short* __restrict__ Kp, short* __restrict__ Vp)
{
    __shared__ short xs[32][1032];    // 32 rows x 1024 k (+8 pad) bf16 = 66 KB

    const int t = threadIdx.x;
    const int w = t >> 6, lane = t & 63, col = lane & 15, quad = lane >> 4;
    const int row0 = blockIdx.x * 32;

    // ---- stage x tile (32 x 1024 fp32 -> bf16 LDS), coalesced
    #pragma unroll
    for (int rr = 0; rr < 32; ++rr) {
        float4 f = *(const float4*)&x[(size_t)(row0 + rr) * D_ + t * 4];
        bf16x4 v;
        v[0] = f2bf(f.x); v[1] = f2bf(f.y); v[2] = f2bf(f.z); v[3] = f2bf(f.w);
        *(bf16x4*)&xs[rr][t * 4] = v;
    }

    // W-frag base for this wave (frags fid = w*3 + {0,1,2})
    const short* __restrict__ wb = Wfp + (size_t)(w * 3) * 32 * 512 + lane * 8;

    bf16x8 wfb[2][3];                 // depth-2 W prefetch
    auto load_W = [&](bf16x8 (&d)[3], int ks) {
        #pragma unroll
        for (int i = 0; i < 3; ++i)
            d[i] = *(const bf16x8*)&wb[((size_t)i * 32 + ks) * 512];
    };
    load_W(wfb[0], 0);
    load_W(wfb[1], 1);

    __syncthreads();                  // xs ready

    bf16x8 xab[2][2];                 // depth-1 A prefetch (mt=0,1)
    auto load_A = [&](bf16x8 (&d)[2], int ks) {
        d[0] = *(const bf16x8*)&xs[col][ks * 32 + quad * 8];
        d[1] = *(const bf16x8*)&xs[16 + col][ks * 32 + quad * 8];
    };
    load_A(xab[0], 0);

    f32x4 acc[2][3] = {};
    for (int ks = 0; ks < 32; ++ks) {
        const int cur = ks & 1;
        if (ks + 1 < 32) load_A(xab[cur ^ 1], ks + 1);
        #pragma unroll
        for (int nt = 0; nt < 3; ++nt) {
            acc[0][nt] = __builtin_amdgcn_mfma_f32_16x16x32_bf16(xab[cur][0], wfb[cur][nt], acc[0][nt], 0, 0, 0);
            acc[1][nt] = __builtin_amdgcn_mfma_f32_16x16x32_bf16(xab[cur][1], wfb[cur][nt], acc[1][nt], 0, 0, 0);
        }
        if (ks + 2 < 32) load_W(wfb[cur], ks + 2);
    }

    // ---- epilogue: C (32x192) -> LDS bounce (overlay xs) -> packed frags
    __syncthreads();                  // xs no longer needed
    short (*Cs)[200] = (short(*)[200])&xs[0][0];
    #pragma unroll
    for (int mt = 0; mt < 2; ++mt)
        #pragma unroll
        for (int nt = 0; nt < 3; ++nt)
            #pragma unroll
            for (int r = 0; r < 4; ++r)
                Cs[mt * 16 + quad * 4 + r][w * 48 + nt * 16 + col] = f2bf(acc[mt][nt][r]);
    __syncthreads();

    const int qtile = row0 >> 4;          // global 16-row tile
    const int ktg   = row0 >> 6;          // global 64-row tile
    const int half  = (row0 >> 5) & 1;    // which 32-row half of the 64-tile

    if (w < 2) {
        // Q: waves 0,1 -> q-tile (qtile+w), frags f=0,1
        #pragma unroll
        for (int f = 0; f < 2; ++f) {
            bf16x8 v = *(const bf16x8*)&Cs[w * 16 + col][f * 32 + quad * 8];
            *(bf16x8*)&Qp[((size_t)(qtile + w) * 2 + f) * 512 + lane * 8] = v;
        }
    } else {
        // K: waves 2,3 -> ks = w-2, nt = half*2 + {0,1}
        const int ks = w - 2;
        #pragma unroll
        for (int ntl = 0; ntl < 2; ++ntl) {
            const int nt = half * 2 + ntl;
            bf16x8 v = *(const bf16x8*)&Cs[ntl * 16 + col][64 + ks * 32 + quad * 8];
            *(bf16x8*)&Kp[((size_t)(ktg * 4 + nt) * 2 + ks) * 512 + lane * 8] = v;
        }
    }
    {
        // V: wave w -> nt = w, ks = half (keys are this block's 32 rows)
        const int nt = w;
        bf16x8 v;
        #pragma unroll
        for (int jj = 0; jj < 8; ++jj)
            v[jj] = Cs[quad * 8 + jj][128 + nt * 16 + col];
        *(bf16x8*)&Vp[((size_t)(ktg * 2 + half) * 4 + nt) * 512 + lane * 8] = v;
    }
}

// ---------------------------------------------------------------------------
// Kernel 2: causal flash attention, bf16 MFMA, fp32 acc, log2-domain softmax.
// Block = 16 queries, 4 waves = 4-way KEY split (wave w: kt = w, w+4, ...).
// Grid 8*128 = 1024. All frag loads coalesced from packed layouts. K-frag
// prefetch reloads kc in place right after the S-MFMAs consume it (no extra
// buffer -> lower VGPR). b = bi&7 keeps each batch's 1 MB K/V on one XCD L2.
// ---------------------------------------------------------------------------
__global__ __launch_bounds__(256) void attn(
    const short* __restrict__ Qp, const short* __restrict__ Kp,
    const short* __restrict__ Vp, float* __restrict__ outp)
{
    __shared__ short Ps[4][16][72];      // per-wave P tile (bf16)
    __shared__ float pO[3][16][68];      // waves 1-3 partial O
    __shared__ float pml[2][3][16];      // [m|l][wave-1][row]

    const int bi = blockIdx.x;
    const int j  = 127 - (bi >> 3);      // 16-q tile, heaviest first
    const int b  = bi & 7;
    const int t  = threadIdx.x;
    const int w = t >> 6, lane = t & 63, col = lane & 15, quad = lane >> 4;
    const int qbase = j * 16;
    const int nkt = (j + 4) >> 2;        // ceil(16*(j+1)/64)
    const int gbase = b * 32;            // global 64-key tile base for batch b

    // Q fragments: coalesced packed loads
    const short* Qpb = Qp + ((size_t)(b * 128 + j) * 2) * 512;
    const bf16x8 aq0 = *(const bf16x8*)&Qpb[lane * 8];
    const bf16x8 aq1 = *(const bf16x8*)&Qpb[512 + lane * 8];

    f32x4 Oacc[4] = {};
    float m[4] = {-INFINITY, -INFINITY, -INFINITY, -INFINITY};
    float l[4] = {0.f, 0.f, 0.f, 0.f};

    auto load_K = [&](bf16x8 (&dst)[4][2], int g) {
        const short* base = Kp + (size_t)g * 4096;
        #pragma unroll
        for (int nt = 0; nt < 4; ++nt) {
            dst[nt][0] = *(const bf16x8*)&base[nt * 1024 + lane * 8];
            dst[nt][1] = *(const bf16x8*)&base[nt * 1024 + 512 + lane * 8];
        }
    };

    bf16x8 kc[4][2];
    if (w < nkt) load_K(kc, gbase + w);

    for (int kt = w; kt < nkt; kt += 4) {
        const int kbase = kt * 64;

        // ---- S = Q K^T (16q x 64k)
        f32x4 S[4] = {};
        #pragma unroll
        for (int nt = 0; nt < 4; ++nt) {
            S[nt] = __builtin_amdgcn_mfma_f32_16x16x32_bf16(aq0, kc[nt][0], S[nt], 0, 0, 0);
            S[nt] = __builtin_amdgcn_mfma_f32_16x16x32_bf16(aq1, kc[nt][1], S[nt], 0, 0, 0);
        }

        // ---- in-place K prefetch for kt+4 (consumed next iter, ~600 cyc away)
        if (kt + 4 < nkt) load_K(kc, gbase + kt + 4);

        // ---- V loads for this tile; softmax below hides their latency
        const short* vb = Vp + (size_t)(gbase + kt) * 4096;
        bf16x8 vv[2][4];
        #pragma unroll
        for (int ks = 0; ks < 2; ++ks)
            #pragma unroll
            for (int nt = 0; nt < 4; ++nt)
                vv[ks][nt] = *(const bf16x8*)&vb[(ks * 4 + nt) * 512 + lane * 8];

        // ---- causal mask (only final, diagonal-overlap tile)
        if (kbase + 63 > qbase) {
            #pragma unroll
            for (int nt = 0; nt < 4; ++nt) {
                const int key = kbase + nt * 16 + col;
                #pragma unroll
                for (int r = 0; r < 4; ++r)
                    if (key > qbase + quad * 4 + r) S[nt][r] = -INFINITY;
            }
        }

        // ---- online softmax, log2 domain (scores pre-scaled by log2(e))
        float alpha[4];
        #pragma unroll
        for (int r = 0; r < 4; ++r) {
            float mx = fmaxf(fmaxf(S[0][r], S[1][r]), fmaxf(S[2][r], S[3][r]));
            mx = fmaxf(mx, __shfl_xor(mx, 1));
            mx = fmaxf(mx, __shfl_xor(mx, 2));
            mx = fmaxf(mx, __shfl_xor(mx, 4));
            mx = fmaxf(mx, __shfl_xor(mx, 8));
            const float mn = fmaxf(m[r], mx);
            alpha[r] = __builtin_amdgcn_exp2f(m[r] - mn);   // first tile: 0
            m[r] = mn;
            float rs = 0.f;
            #pragma unroll
            for (int nt = 0; nt < 4; ++nt) {
                const float p = __builtin_amdgcn_exp2f(S[nt][r] - mn);
                S[nt][r] = p;
                rs += p;
            }
            rs += __shfl_xor(rs, 1);
            rs += __shfl_xor(rs, 2);
            rs += __shfl_xor(rs, 4);
            rs += __shfl_xor(rs, 8);
            l[r] = l[r] * alpha[r] + rs;
        }
        #pragma unroll
        for (int nt = 0; nt < 4; ++nt)
            #pragma unroll
            for (int r = 0; r < 4; ++r) Oacc[nt][r] *= alpha[r];

        // ---- P: C layout -> bf16 -> wave-private LDS (transpose to A layout)
        #pragma unroll
        for (int nt = 0; nt < 4; ++nt)
            #pragma unroll
            for (int r = 0; r < 4; ++r)
                Ps[w][quad * 4 + r][nt * 16 + col] = f2bf(S[nt][r]);
        __asm__ volatile("s_waitcnt lgkmcnt(0)" ::: "memory");

        // ---- O += P V
        #pragma unroll
        for (int ks = 0; ks < 2; ++ks) {
            bf16x8 ap = *(const bf16x8*)&Ps[w][col][ks * 32 + quad * 8];
            #pragma unroll
            for (int nt = 0; nt < 4; ++nt)
                Oacc[nt] = __builtin_amdgcn_mfma_f32_16x16x32_bf16(ap, vv[ks][nt], Oacc[nt], 0, 0, 0);
        }
    }

    // ---- 4-way partial merge (waves 1-3 publish; wave 0 combines + stores)
    __syncthreads();
    if (w > 0) {
        #pragma unroll
        for (int nt = 0; nt < 4; ++nt)
            #pragma unroll
            for (int r = 0; r < 4; ++r)
                pO[w - 1][quad * 4 + r][nt * 16 + col] = Oacc[nt][r];
        if (col == 0) {
            #pragma unroll
            for (int r = 0; r < 4; ++r) {
                pml[0][w - 1][quad * 4 + r] = m[r];
                pml[1][w - 1][quad * 4 + r] = l[r];
            }
        }
    }
    __syncthreads();
    if (w == 0) {
        #pragma unroll
        for (int r = 0; r < 4; ++r) {
            const int row = quad * 4 + r;
            float M = m[r];
            #pragma unroll
            for (int i = 0; i < 3; ++i) M = fmaxf(M, pml[0][i][row]);
            const float a0 = __builtin_amdgcn_exp2f(m[r] - M);
            float ai[3];
            float L = a0 * l[r];
            #pragma unroll
            for (int i = 0; i < 3; ++i) {
                ai[i] = __builtin_amdgcn_exp2f(pml[0][i][row] - M);  // -inf -> 0
                L += ai[i] * pml[1][i][row];
            }
            const float inv = 1.0f / L;
            float* dst = outp + (size_t)(b * S_ + qbase + row) * H_;
            #pragma unroll
            for (int nt = 0; nt < 4; ++nt) {
                float v = a0 * Oacc[nt][r];
                #pragma unroll
                for (int i = 0; i < 3; ++i) v += ai[i] * pO[i][row][nt * 16 + col];
                dst[nt * 16 + col] = v * inv;
            }
        }
    }
}

// ---------------------------------------------------------------------------
extern "C" void kernel_launch(void* const* d_in, const int* in_sizes, int n_in,
                              void* d_out, int out_size, void* d_ws, size_t ws_size,
                              hipStream_t stream)
{
    const float* x  = (const float*)d_in[0];
    const float* Wq = (const float*)d_in[1];
    const float* Wk = (const float*)d_in[2];
    const float* Wv = (const float*)d_in[3];
    float* out = (float*)d_out;

    short* Qp  = (short*)d_ws;            // 1024 qtiles * 2 frags * 512  (2 MB)
    short* Kp  = Qp + (size_t)BS_ * H_;   // 256 ktiles * 8 frags * 512   (2 MB)
    short* Vp  = Kp + (size_t)BS_ * H_;   // 256 ktiles * 8 frags * 512   (2 MB)
    short* Wfp = Vp + (size_t)BS_ * H_;   // 12 frag-cols * 32 ks * 512   (384 KB)

    hipLaunchKernelGGL(wprep,    dim3(32), dim3(256), 0, stream, Wq, Wk, Wv, Wfp);
    hipLaunchKernelGGL(qkv_proj, dim3(BS_ / 32), dim3(256), 0, stream, x, Wfp, Qp, Kp, Vp);
    hipLaunchKernelGGL(attn,     dim3(B_ * (S_ / 16)), dim3(256), 0, stream, Qp, Kp, Vp, out);
}